// Round 1
// baseline (24719.601 us; speedup 1.0000x reference)
//
#include <hip/hip_runtime.h>
#include <hip/hip_cooperative_groups.h>
#include <cmath>

namespace cg = cooperative_groups;

static constexpr int Bn = 64, Tn = 512, Fn = 784, Hn = 512, G4n = 2048, On = 10;
static constexpr long XZ_ELEMS   = (long)Bn * Tn * G4n;   // 67,108,864 (256 MB)
static constexpr long HSEQ_ELEMS = (long)Bn * Tn * Hn;    // 16,777,216 (64 MB)

// ---------------- K1: xz = x @ W + b ----------------
// M=32768, K=784 (=49*16), N=2048. 64x64 tile, 4x4 microtile, 256 threads.
__global__ __launch_bounds__(256) void gemm_xz(
    const float* __restrict__ A, const float* __restrict__ W,
    const float* __restrict__ bias, float* __restrict__ C)
{
  __shared__ float As[16][68];  // A^T tile, +4 pad keeps float4 alignment, 2-way banks
  __shared__ float Bs[16][68];
  const int tid = threadIdx.x;
  const int tx = tid & 15, ty = tid >> 4;
  const int n0 = blockIdx.x * 64, m0 = blockIdx.y * 64;
  const int ar = tid >> 2, ac = (tid & 3) << 2;   // A: 64 rows x 16k, one float4/thread
  const int br = tid >> 4, bc = (tid & 15) << 2;  // B: 16k x 64 cols, one float4/thread
  float acc[4][4] = {};
  for (int kt = 0; kt < Fn; kt += 16) {
    const float4 a4 = *(const float4*)(A + (size_t)(m0 + ar) * Fn + kt + ac);
    const float4 b4 = *(const float4*)(W + (size_t)(kt + br) * G4n + n0 + bc);
    __syncthreads();
    As[ac + 0][ar] = a4.x; As[ac + 1][ar] = a4.y;
    As[ac + 2][ar] = a4.z; As[ac + 3][ar] = a4.w;
    *(float4*)(&Bs[br][bc]) = b4;
    __syncthreads();
#pragma unroll
    for (int k = 0; k < 16; ++k) {
      const float4 av = *(const float4*)(&As[k][ty << 2]);
      const float4 bv = *(const float4*)(&Bs[k][tx << 2]);
      const float aarr[4] = {av.x, av.y, av.z, av.w};
      const float barr[4] = {bv.x, bv.y, bv.z, bv.w};
#pragma unroll
      for (int i = 0; i < 4; ++i)
#pragma unroll
        for (int j = 0; j < 4; ++j)
          acc[i][j] = fmaf(aarr[i], barr[j], acc[i][j]);
    }
  }
  const float4 bias4 = *(const float4*)(bias + n0 + (tx << 2));
  const float bb4[4] = {bias4.x, bias4.y, bias4.z, bias4.w};
#pragma unroll
  for (int i = 0; i < 4; ++i) {
    float4 ov;
    ov.x = acc[i][0] + bb4[0];
    ov.y = acc[i][1] + bb4[1];
    ov.z = acc[i][2] + bb4[2];
    ov.w = acc[i][3] + bb4[3];
    *(float4*)(C + (size_t)(m0 + (ty << 2) + i) * G4n + n0 + (tx << 2)) = ov;
  }
}

// ---------------- K2: persistent cooperative LSTM recurrence ----------------
// 256 blocks x 256 threads. Block g owns h-columns {2g, 2g+1} for ALL batches:
// gate columns {j, 512+j, 1024+j, 1536+j} for j in {2g, 2g+1} (Keras order i,f,g,o).
// U slice (8 cols x 512) transposed into LDS ONCE; h double-buffered in global,
// one grid.sync() per timestep. c-state lives in LDS for the whole sequence.
__global__ __launch_bounds__(256) void lstm_coop(
    const float* __restrict__ xz, const float* __restrict__ U,
    float* __restrict__ hbuf, float* __restrict__ h_seq)
{
  cg::grid_group grid = cg::this_grid();
  const int blk = blockIdx.x;   // 0..255
  const int tid = threadIdx.x;  // 0..255
  __shared__ float Ut[8][516];   // U^T slice; stride 516: 16B-aligned rows, spread banks
  __shared__ float zbuf[64][9];  // gate pre-activations, padded
  __shared__ float cbuf[64][2];  // c-state for this block's 2 h-cols

  // one-time: stage this block's U columns, transposed
  for (int i = tid; i < 8 * 512; i += 256) {
    const int c8 = i >> 9;      // 0..7  (gate*2 + jj)
    const int k  = i & 511;
    const int col = ((c8 >> 1) << 9) + (blk << 1) + (c8 & 1);
    Ut[c8][k] = U[(size_t)k * G4n + col];
  }
  if (tid < 128) cbuf[tid & 63][tid >> 6] = 0.f;
  {   // zero h_0 (blocks 0..127 cover all 64*512 entries of buffer 0)
    const int g = blk * 256 + tid;
    if (g < Bn * Hn) hbuf[g] = 0.f;
  }
  grid.sync();

  const int c8 = tid & 7;       // which of the 8 gate-columns
  const int brow = tid >> 3;    // 0..31 -> batches brow and brow+32
  const int gate = c8 >> 1, jj = c8 & 1;
  const int gcol = (gate << 9) + (blk << 1) + jj;

  int cur = 0;
  for (int t = 0; t < Tn; ++t) {
    const float* h0p = hbuf + cur * (Bn * Hn) + (brow << 9);
    const float* h1p = h0p + (32 << 9);
    const float* up = &Ut[c8][0];
    float acc0 = 0.f, acc1 = 0.f;
#pragma unroll 4
    for (int k = 0; k < Hn; k += 4) {
      const float4 u4 = *(const float4*)(up + k);
      const float4 ha = *(const float4*)(h0p + k);
      const float4 hb = *(const float4*)(h1p + k);
      acc0 = fmaf(ha.x, u4.x, acc0);
      acc0 = fmaf(ha.y, u4.y, acc0);
      acc0 = fmaf(ha.z, u4.z, acc0);
      acc0 = fmaf(ha.w, u4.w, acc0);
      acc1 = fmaf(hb.x, u4.x, acc1);
      acc1 = fmaf(hb.y, u4.y, acc1);
      acc1 = fmaf(hb.z, u4.z, acc1);
      acc1 = fmaf(hb.w, u4.w, acc1);
    }
    zbuf[brow][c8]      = xz[((size_t)brow * Tn + t) * G4n + gcol] + acc0;
    zbuf[brow + 32][c8] = xz[((size_t)(brow + 32) * Tn + t) * G4n + gcol] + acc1;
    __syncthreads();
    if (tid < 128) {
      const int bb = tid & 63, j = tid >> 6;
      const float zi = zbuf[bb][0 + j];
      const float zf = zbuf[bb][2 + j];
      const float zg = zbuf[bb][4 + j];
      const float zo = zbuf[bb][6 + j];
      const float iv = 1.f / (1.f + expf(-zi));
      const float fv = 1.f / (1.f + expf(-zf));
      const float gv = tanhf(zg);
      const float ov = 1.f / (1.f + expf(-zo));
      const float cv = fv * cbuf[bb][j] + iv * gv;
      cbuf[bb][j] = cv;
      const float hv = ov * tanhf(cv);
      const int col = (blk << 1) + j;
      hbuf[(cur ^ 1) * (Bn * Hn) + (bb << 9) + col] = hv;
      h_seq[((size_t)bb * Tn + t) * Hn + col] = hv;
    }
    grid.sync();   // full barrier (block + grid): h_{t} visible, zbuf/cbuf safe to reuse
    cur ^= 1;
  }
}

// ---------------- K3: out = h_seq @ Wd + bd ----------------
// 327680 outputs, one thread each; Wd transposed into LDS.
__global__ __launch_bounds__(256) void proj_out(
    const float* __restrict__ h_seq, const float* __restrict__ Wd,
    const float* __restrict__ bd, float* __restrict__ out)
{
  __shared__ float Wdt[10][516];
  for (int i = threadIdx.x; i < Hn * On; i += 256) {
    const int k = i / 10, o = i - k * 10;
    Wdt[o][k] = Wd[i];
  }
  __syncthreads();
  const int idx = blockIdx.x * 256 + threadIdx.x;  // grid is exact: 1280*256 = 327680
  const int row = idx / 10, o = idx - row * 10;
  const float* hp = h_seq + (size_t)row * Hn;
  const float* wp = &Wdt[o][0];
  float acc = bd[o];
#pragma unroll 4
  for (int k = 0; k < Hn; k += 4) {
    const float4 h4 = *(const float4*)(hp + k);
    const float4 w4 = *(const float4*)(wp + k);
    acc = fmaf(h4.x, w4.x, acc);
    acc = fmaf(h4.y, w4.y, acc);
    acc = fmaf(h4.z, w4.z, acc);
    acc = fmaf(h4.w, w4.w, acc);
  }
  out[idx] = acc;
}

extern "C" void kernel_launch(void* const* d_in, const int* in_sizes, int n_in,
                              void* d_out, int out_size, void* d_ws, size_t ws_size,
                              hipStream_t stream)
{
  const float* x  = (const float*)d_in[0];
  const float* W  = (const float*)d_in[1];
  const float* U  = (const float*)d_in[2];
  const float* b  = (const float*)d_in[3];
  const float* Wd = (const float*)d_in[4];
  const float* bd = (const float*)d_in[5];
  float* out = (float*)d_out;

  // workspace layout (fp32): xz [64,512,2048] | h_seq [64,512,512] | hbuf [2,64,512]
  float* xz    = (float*)d_ws;
  float* h_seq = xz + XZ_ELEMS;
  float* hbuf  = h_seq + HSEQ_ELEMS;

  gemm_xz<<<dim3(G4n / 64, (Bn * Tn) / 64), 256, 0, stream>>>(x, W, b, xz);

  void* args[] = { (void*)&xz, (void*)&U, (void*)&hbuf, (void*)&h_seq };
  hipLaunchCooperativeKernel((void*)lstm_coop, dim3(256), dim3(256), args, 0, stream);

  proj_out<<<(Bn * Tn * On) / 256, 256, 0, stream>>>(h_seq, Wd, bd, out);
}

// Round 2
// 18627.048 us; speedup vs baseline: 1.3271x; 1.3271x over previous
//
#include <hip/hip_runtime.h>
#include <hip/hip_cooperative_groups.h>
#include <cmath>

namespace cg = cooperative_groups;

static constexpr int Bn = 64, Tn = 512, Fn = 784, Hn = 512, G4n = 2048, On = 10;
static constexpr long XZ_ELEMS   = (long)Bn * Tn * G4n;   // 67,108,864 (256 MB)
static constexpr long HSEQ_ELEMS = (long)Bn * Tn * Hn;    // 16,777,216 (64 MB)

// ---------------- K1: xz = x @ W + b ----------------
__global__ __launch_bounds__(256) void gemm_xz(
    const float* __restrict__ A, const float* __restrict__ W,
    const float* __restrict__ bias, float* __restrict__ C)
{
  __shared__ float As[16][68];
  __shared__ float Bs[16][68];
  const int tid = threadIdx.x;
  const int tx = tid & 15, ty = tid >> 4;
  const int n0 = blockIdx.x * 64, m0 = blockIdx.y * 64;
  const int ar = tid >> 2, ac = (tid & 3) << 2;
  const int br = tid >> 4, bc = (tid & 15) << 2;
  float acc[4][4] = {};
  for (int kt = 0; kt < Fn; kt += 16) {
    const float4 a4 = *(const float4*)(A + (size_t)(m0 + ar) * Fn + kt + ac);
    const float4 b4 = *(const float4*)(W + (size_t)(kt + br) * G4n + n0 + bc);
    __syncthreads();
    As[ac + 0][ar] = a4.x; As[ac + 1][ar] = a4.y;
    As[ac + 2][ar] = a4.z; As[ac + 3][ar] = a4.w;
    *(float4*)(&Bs[br][bc]) = b4;
    __syncthreads();
#pragma unroll
    for (int k = 0; k < 16; ++k) {
      const float4 av = *(const float4*)(&As[k][ty << 2]);
      const float4 bv = *(const float4*)(&Bs[k][tx << 2]);
      const float aarr[4] = {av.x, av.y, av.z, av.w};
      const float barr[4] = {bv.x, bv.y, bv.z, bv.w};
#pragma unroll
      for (int i = 0; i < 4; ++i)
#pragma unroll
        for (int j = 0; j < 4; ++j)
          acc[i][j] = fmaf(aarr[i], barr[j], acc[i][j]);
    }
  }
  const float4 bias4 = *(const float4*)(bias + n0 + (tx << 2));
  const float bb4[4] = {bias4.x, bias4.y, bias4.z, bias4.w};
#pragma unroll
  for (int i = 0; i < 4; ++i) {
    float4 ov;
    ov.x = acc[i][0] + bb4[0];
    ov.y = acc[i][1] + bb4[1];
    ov.z = acc[i][2] + bb4[2];
    ov.w = acc[i][3] + bb4[3];
    *(float4*)(C + (size_t)(m0 + (ty << 2) + i) * G4n + n0 + (tx << 2)) = ov;
  }
}

// ---------------- K2: persistent cooperative LSTM recurrence (v2) ----------------
// Grid 256 = 4 batch-groups x 64 h-groups; 512 threads (8 waves).
// Block (bgrp, hgrp): batches [bgrp*16, +16), h-cols [hgrp*8, +8) => 32 gate cols.
// U slice (32 cols x 512 k, fp32, transposed) in LDS for the whole sequence.
// Per step: stage h-slice [16 x 512] from h_seq[:, t-1, :] into LDS (32 KB),
// every thread does ONE 512-length LDS dot (U 4-way padded-bank, h broadcast),
// 128 threads do the pointwise gates, write h directly to h_seq[:, t, :].
// One grid.sync per step.
__global__ __launch_bounds__(512) void lstm_coop(
    const float* __restrict__ xz, const float* __restrict__ U,
    float* __restrict__ h_seq)
{
  cg::grid_group grid = cg::this_grid();
  const int tid  = threadIdx.x;
  const int bgrp = blockIdx.x >> 6;   // 0..3
  const int hgrp = blockIdx.x & 63;   // 0..63

  __shared__ float Uts[32][516];   // [gate-col][k], +4 pad -> 4-way banks on b128
  __shared__ float hs[16][516];    // h slice for this bgrp's batches
  __shared__ float zb[16][36];     // gate pre-activations
  __shared__ float cb[16][8];      // c-state

  // one-time: stage U columns (transposed)
  for (int i = tid; i < 32 * 512; i += 512) {
    const int c = i >> 9, k = i & 511;
    const int gcol = ((c >> 3) << 9) + (hgrp << 3) + (c & 7);
    Uts[c][k] = U[(size_t)k * G4n + gcol];
  }
  {
    float* hsf = &hs[0][0];
    for (int i = tid; i < 16 * 516; i += 512) hsf[i] = 0.f;
  }
  if (tid < 128) cb[tid >> 3][tid & 7] = 0.f;
  grid.sync();

  // dot-product assignment: wave w, lane l -> col c = l&31, batch bq = 2w + (l>>5)
  const int w = tid >> 6, l = tid & 63;
  const int c = l & 31;
  const int bq = (w << 1) + (l >> 5);        // 0..15
  const int bglob = (bgrp << 4) + bq;
  const int gcol = ((c >> 3) << 9) + (hgrp << 3) + (c & 7);
  const float* xzp = xz + (size_t)bglob * (Tn * G4n) + gcol;

  // h-stage assignment: 4 float4 per thread
  const int sb = tid >> 7;                    // base pattern below

  for (int t = 0; t < Tn; ++t) {
    if (t > 0) {
#pragma unroll
      for (int j = 0; j < 4; ++j) {
        const int i = tid + (j << 9);         // 0..2047 float4 slots
        const int b = i >> 7;                 // 0..15
        const int f4 = i & 127;               // float4 index within row
        const float4 v = *(const float4*)(h_seq +
            ((size_t)((bgrp << 4) + b) * Tn + (t - 1)) * Hn + (f4 << 2));
        *(float4*)(&hs[b][f4 << 2]) = v;
      }
    }
    __syncthreads();

    // issue xz read early (independent of LDS dot)
    const float xzv = xzp[(size_t)t * G4n];

    float acc = 0.f;
    const float* up = &Uts[c][0];
    const float* hp = &hs[bq][0];
#pragma unroll 4
    for (int k = 0; k < Hn; k += 4) {
      const float4 u4 = *(const float4*)(up + k);
      const float4 h4 = *(const float4*)(hp + k);
      acc = fmaf(h4.x, u4.x, acc);
      acc = fmaf(h4.y, u4.y, acc);
      acc = fmaf(h4.z, u4.z, acc);
      acc = fmaf(h4.w, u4.w, acc);
    }
    zb[bq][c] = xzv + acc;
    __syncthreads();

    if (tid < 128) {
      const int b = tid >> 3, jj = tid & 7;
      const float zi = zb[b][jj];
      const float zf = zb[b][8 + jj];
      const float zg = zb[b][16 + jj];
      const float zo = zb[b][24 + jj];
      const float iv = 1.f / (1.f + expf(-zi));
      const float fv = 1.f / (1.f + expf(-zf));
      const float gv = tanhf(zg);
      const float ov = 1.f / (1.f + expf(-zo));
      const float cv = fv * cb[b][jj] + iv * gv;
      cb[b][jj] = cv;
      const float hv = ov * tanhf(cv);
      h_seq[((size_t)((bgrp << 4) + b) * Tn + t) * Hn + (hgrp << 3) + jj] = hv;
    }
    grid.sync();   // h_t visible device-wide; hs/zb safe to overwrite
  }
  (void)sb;
}

// ---------------- K3: out = h_seq @ Wd + bd ----------------
__global__ __launch_bounds__(256) void proj_out(
    const float* __restrict__ h_seq, const float* __restrict__ Wd,
    const float* __restrict__ bd, float* __restrict__ out)
{
  __shared__ float Wdt[10][516];
  for (int i = threadIdx.x; i < Hn * On; i += 256) {
    const int k = i / 10, o = i - k * 10;
    Wdt[o][k] = Wd[i];
  }
  __syncthreads();
  const int idx = blockIdx.x * 256 + threadIdx.x;
  const int row = idx / 10, o = idx - row * 10;
  const float* hp = h_seq + (size_t)row * Hn;
  const float* wp = &Wdt[o][0];
  float acc = bd[o];
#pragma unroll 4
  for (int k = 0; k < Hn; k += 4) {
    const float4 h4 = *(const float4*)(hp + k);
    const float4 w4 = *(const float4*)(wp + k);
    acc = fmaf(h4.x, w4.x, acc);
    acc = fmaf(h4.y, w4.y, acc);
    acc = fmaf(h4.z, w4.z, acc);
    acc = fmaf(h4.w, w4.w, acc);
  }
  out[idx] = acc;
}

extern "C" void kernel_launch(void* const* d_in, const int* in_sizes, int n_in,
                              void* d_out, int out_size, void* d_ws, size_t ws_size,
                              hipStream_t stream)
{
  const float* x  = (const float*)d_in[0];
  const float* W  = (const float*)d_in[1];
  const float* U  = (const float*)d_in[2];
  const float* b  = (const float*)d_in[3];
  const float* Wd = (const float*)d_in[4];
  const float* bd = (const float*)d_in[5];
  float* out = (float*)d_out;

  // workspace layout (fp32): xz [64,512,2048] | h_seq [64,512,512]
  float* xz    = (float*)d_ws;
  float* h_seq = xz + XZ_ELEMS;

  gemm_xz<<<dim3(G4n / 64, (Bn * Tn) / 64), 256, 0, stream>>>(x, W, b, xz);

  void* args[] = { (void*)&xz, (void*)&U, (void*)&h_seq };
  hipLaunchCooperativeKernel((void*)lstm_coop, dim3(256), dim3(512), args, 0, stream);

  proj_out<<<(Bn * Tn * On) / 256, 256, 0, stream>>>(h_seq, Wd, bd, out);
}

// Round 5
// 11558.750 us; speedup vs baseline: 2.1386x; 1.6115x over previous
//
#include <hip/hip_runtime.h>
#include <cmath>

typedef __attribute__((ext_vector_type(8))) short bf16x8;
typedef __attribute__((ext_vector_type(4))) float f32x4;

static constexpr int Bn = 64, Tn = 512, Fn = 784, Hn = 512, G4n = 2048, On = 10;
static constexpr int NBLK = 128;
static constexpr long XZ_ELEMS   = (long)Bn * Tn * G4n;   // 256 MB
static constexpr long HSEQ_ELEMS = (long)Bn * Tn * Hn;    // 64 MB
// ws layout: xz f32 | h_seq f32 | hfrag 2x32768 ushort | barrier counter

__device__ __forceinline__ ushort f2bf(float x) {   // RNE fp32->bf16
  uint b = __float_as_uint(x);
  uint r = (b + 0x7FFFu + ((b >> 16) & 1u)) >> 16;
  return (ushort)r;
}
__device__ __forceinline__ float bf2f(ushort h) {
  return __uint_as_float(((uint)h) << 16);
}

// device-scope grid barrier: monotonic counter, one arrival per block.
// Protocol (classic multi-block barrier, same as cg grid.sync implements):
// release-fence -> block barrier -> t0: arrive + spin to target -> acquire-fence
// -> block barrier.
__device__ __forceinline__ void gridbar(uint* cnt, uint target) {
  __threadfence();            // release this thread's prior global stores
  __syncthreads();
  if (threadIdx.x == 0) {
    atomicAdd(cnt, 1u);       // device-scope by default (G12/m20)
    while (__hip_atomic_load(cnt, __ATOMIC_RELAXED, __HIP_MEMORY_SCOPE_AGENT) < target)
      __builtin_amdgcn_s_sleep(2);
    __threadfence();          // acquire
  }
  __syncthreads();
}

// ---------------- K1: xz = x @ W + b (fp32, unchanged from passing R2) ----------------
__global__ __launch_bounds__(256) void gemm_xz(
    const float* __restrict__ A, const float* __restrict__ W,
    const float* __restrict__ bias, float* __restrict__ C)
{
  __shared__ float As[16][68];
  __shared__ float Bs[16][68];
  const int tid = threadIdx.x;
  const int tx = tid & 15, ty = tid >> 4;
  const int n0 = blockIdx.x * 64, m0 = blockIdx.y * 64;
  const int ar = tid >> 2, ac = (tid & 3) << 2;
  const int br = tid >> 4, bc = (tid & 15) << 2;
  float acc[4][4] = {};
  for (int kt = 0; kt < Fn; kt += 16) {
    const float4 a4 = *(const float4*)(A + (size_t)(m0 + ar) * Fn + kt + ac);
    const float4 b4 = *(const float4*)(W + (size_t)(kt + br) * G4n + n0 + bc);
    __syncthreads();
    As[ac + 0][ar] = a4.x; As[ac + 1][ar] = a4.y;
    As[ac + 2][ar] = a4.z; As[ac + 3][ar] = a4.w;
    *(float4*)(&Bs[br][bc]) = b4;
    __syncthreads();
#pragma unroll
    for (int k = 0; k < 16; ++k) {
      const float4 av = *(const float4*)(&As[k][ty << 2]);
      const float4 bv = *(const float4*)(&Bs[k][tx << 2]);
      const float aarr[4] = {av.x, av.y, av.z, av.w};
      const float barr[4] = {bv.x, bv.y, bv.z, bv.w};
#pragma unroll
      for (int i = 0; i < 4; ++i)
#pragma unroll
        for (int j = 0; j < 4; ++j)
          acc[i][j] = fmaf(aarr[i], barr[j], acc[i][j]);
    }
  }
  const float4 bias4 = *(const float4*)(bias + n0 + (tx << 2));
  const float bb4[4] = {bias4.x, bias4.y, bias4.z, bias4.w};
#pragma unroll
  for (int i = 0; i < 4; ++i) {
    float4 ov;
    ov.x = acc[i][0] + bb4[0];
    ov.y = acc[i][1] + bb4[1];
    ov.z = acc[i][2] + bb4[2];
    ov.w = acc[i][3] + bb4[3];
    *(float4*)(C + (size_t)(m0 + (ty << 2) + i) * G4n + n0 + (tx << 2)) = ov;
  }
}

// ---------------- K2: MFMA LSTM recurrence (transposed tile, plain launch) ----------------
// 128 blocks x 256 thr (>=1 block/CU guaranteed resident; no LDS, <=256 VGPR).
// Block owns h-cols [4*blk, +4). A = U^T (16 rows = gate r + hcol kg), static in
// regs as bf16 hi+lo. B = h^T (16 cols = wave's batches) from packed global
// hfrag (double-buffered). C/D map (m89): lane(kg,n) reg r = z[gate r][hcol
// blk*4+kg][batch 16w+n] -> all 4 gates in one lane, no cross-lane ops.
__global__ __launch_bounds__(256) void lstm_mfma(
    const float* __restrict__ xz, const float* __restrict__ U,
    float* __restrict__ h_seq, ushort* __restrict__ hfrag, uint* __restrict__ cnt)
{
  const int tid = threadIdx.x;
  const int blk = blockIdx.x;       // 0..127
  const int w = tid >> 6;           // wave -> batch tile (16 batches)
  const int l = tid & 63;
  const int n = l & 15;             // B col = batch within tile; C/D col
  const int kg = l >> 4;            // k group; C/D row group

  // ---- one-time: U^T A-fragments into registers (bf16 hi+lo split) ----
  // A[rho][k] = U[k][ugcol], ugcol = (rho&3)*512 + blk*4 + (rho>>2); rho = n
  const int rho = n;
  const int ugcol = ((rho & 3) << 9) + (blk << 2) + (rho >> 2);
  bf16x8 ufhi[16], uflo[16];
#pragma unroll
  for (int ks = 0; ks < 16; ++ks) {
    bf16x8 hi, lo;
#pragma unroll
    for (int e = 0; e < 8; ++e) {
      const float u = U[(size_t)(32 * ks + 8 * kg + e) * G4n + ugcol];
      const ushort uh = f2bf(u);
      hi[e] = (short)uh;
      lo[e] = (short)f2bf(u - bf2f(uh));
    }
    ufhi[ks] = hi; uflo[ks] = lo;
  }

  // zero hfrag buffer 0 (h_{-1} = 0): 16384 uints over 32768 threads
  {
    const int gid = blk * 256 + tid;
    if (gid < 16384) ((uint*)hfrag)[gid] = 0u;
  }

  const int beta = (w << 4) + n;          // batch this lane owns
  const int hc   = (blk << 2) + kg;       // h-col this lane owns
  const float* xzb = xz + (size_t)beta * Tn * G4n + hc;  // + r*512 per gate
  float cst = 0.f;

  uint tgt = NBLK;
  gridbar(cnt, tgt); tgt += NBLK;   // hfrag[0] zeroed everywhere

  float xzc[4];
#pragma unroll
  for (int r = 0; r < 4; ++r) xzc[r] = xzb[r << 9];   // t = 0

  for (int t = 0; t < Tn; ++t) {
    const int cur = t & 1;
    float xzn[4];
    if (t + 1 < Tn) {
#pragma unroll
      for (int r = 0; r < 4; ++r) xzn[r] = xzb[(size_t)(t + 1) * G4n + (r << 9)];
    } else {
#pragma unroll
      for (int r = 0; r < 4; ++r) xzn[r] = 0.f;
    }

    // B-frags: lane holds B[k = 32*ks + 8*kg + e][col n] = h[16w+n][k]
    const bf16x8* bbase = ((const bf16x8*)hfrag) + (size_t)cur * 4096 + w * 1024 + l;
    f32x4 acch = {0.f, 0.f, 0.f, 0.f};
    f32x4 accl = {0.f, 0.f, 0.f, 0.f};
#pragma unroll
    for (int ks = 0; ks < 16; ++ks) {
      const bf16x8 bfr = bbase[ks * 64];
      acch = __builtin_amdgcn_mfma_f32_16x16x32_bf16(ufhi[ks], bfr, acch, 0, 0, 0);
      accl = __builtin_amdgcn_mfma_f32_16x16x32_bf16(uflo[ks], bfr, accl, 0, 0, 0);
    }

    // reg r = gate r (Keras order i,f,g,o) for (batch beta, hcol hc)
    const float zi = acch[0] + accl[0] + xzc[0];
    const float zf = acch[1] + accl[1] + xzc[1];
    const float zg = acch[2] + accl[2] + xzc[2];
    const float zo = acch[3] + accl[3] + xzc[3];
    const float iv = 1.f / (1.f + expf(-zi));
    const float fv = 1.f / (1.f + expf(-zf));
    const float gv = tanhf(zg);
    const float ov = 1.f / (1.f + expf(-zo));
    cst = fv * cst + iv * gv;
    const float hv = ov * tanhf(cst);

    h_seq[((size_t)beta * Tn + t) * Hn + hc] = hv;
    {
      const int ks2 = hc >> 5, sub = (hc & 31) >> 3, j8 = hc & 7;
      hfrag[(size_t)(cur ^ 1) * 32768 +
            ((((beta >> 4) * 16 + ks2) * 64) + sub * 16 + (beta & 15)) * 8 + j8] = f2bf(hv);
    }
#pragma unroll
    for (int r = 0; r < 4; ++r) xzc[r] = xzn[r];
    gridbar(cnt, tgt); tgt += NBLK;   // h_t visible device-wide
  }
}

// ---------------- K3: out = h_seq @ Wd + bd (unchanged) ----------------
__global__ __launch_bounds__(256) void proj_out(
    const float* __restrict__ h_seq, const float* __restrict__ Wd,
    const float* __restrict__ bd, float* __restrict__ out)
{
  __shared__ float Wdt[10][516];
  for (int i = threadIdx.x; i < Hn * On; i += 256) {
    const int k = i / 10, o = i - k * 10;
    Wdt[o][k] = Wd[i];
  }
  __syncthreads();
  const int idx = blockIdx.x * 256 + threadIdx.x;
  const int row = idx / 10, o = idx - row * 10;
  const float* hp = h_seq + (size_t)row * Hn;
  const float* wp = &Wdt[o][0];
  float acc = bd[o];
#pragma unroll 4
  for (int k = 0; k < Hn; k += 4) {
    const float4 h4 = *(const float4*)(hp + k);
    const float4 w4 = *(const float4*)(wp + k);
    acc = fmaf(h4.x, w4.x, acc);
    acc = fmaf(h4.y, w4.y, acc);
    acc = fmaf(h4.z, w4.z, acc);
    acc = fmaf(h4.w, w4.w, acc);
  }
  out[idx] = acc;
}

extern "C" void kernel_launch(void* const* d_in, const int* in_sizes, int n_in,
                              void* d_out, int out_size, void* d_ws, size_t ws_size,
                              hipStream_t stream)
{
  const float* x  = (const float*)d_in[0];
  const float* W  = (const float*)d_in[1];
  const float* U  = (const float*)d_in[2];
  const float* b  = (const float*)d_in[3];
  const float* Wd = (const float*)d_in[4];
  const float* bd = (const float*)d_in[5];
  float* out = (float*)d_out;

  float* xz     = (float*)d_ws;
  float* h_seq  = xz + XZ_ELEMS;
  ushort* hfrag = (ushort*)(h_seq + HSEQ_ELEMS);
  uint* cnt     = (uint*)(hfrag + 2 * 32768);

  gemm_xz<<<dim3(G4n / 64, (Bn * Tn) / 64), 256, 0, stream>>>(x, W, b, xz);

  hipMemsetAsync(cnt, 0, sizeof(uint), stream);   // barrier counter = 0 (captured node)
  lstm_mfma<<<dim3(NBLK), dim3(256), 0, stream>>>(xz, U, h_seq, hfrag, cnt);

  proj_out<<<(Bn * Tn * On) / 256, 256, 0, stream>>>(h_seq, Wd, bd, out);
}

// Round 6
// 9965.140 us; speedup vs baseline: 2.4806x; 1.1599x over previous
//
#include <hip/hip_runtime.h>
#include <cmath>

typedef __attribute__((ext_vector_type(8))) short bf16x8;
typedef __attribute__((ext_vector_type(4))) float f32x4;

static constexpr int Bn = 64, Tn = 512, Fn = 784, Hn = 512, G4n = 2048, On = 10;
static constexpr int NBLK = 64;                            // 64 blocks x 512 thr
static constexpr long XZ_ELEMS   = (long)Bn * Tn * G4n;    // 256 MB
static constexpr long HSEQ_ELEMS = (long)Bn * Tn * Hn;     // 64 MB
// ws: xz f32 | h_seq f32 | hfrag 2x32768 ushort | bar uint[512]

__device__ __forceinline__ ushort f2bf(float x) {   // RNE fp32->bf16
  uint b = __float_as_uint(x);
  uint r = (b + 0x7FFFu + ((b >> 16) & 1u)) >> 16;
  return (ushort)r;
}
__device__ __forceinline__ float bf2f(ushort h) {
  return __uint_as_float(((uint)h) << 16);
}

// Hierarchical decontended grid barrier (64 blocks = 8 groups x 8).
// bar[g*32] : per-group arrival counters (padded to own 128B line)
// bar[256]  : global promotion counter (own line)
// bar[288]  : go epoch (own line, read-only for pollers)
// Monotonic epochs; bar zeroed once per launch by hipMemsetAsync.
// Order proven in R5: all-thread release fence -> syncthreads -> t0
// arrive/spin/acquire -> syncthreads.
__device__ __forceinline__ void gridbar(uint* bar, uint epoch) {
  __threadfence();            // release prior global stores (all threads)
  __syncthreads();
  if (threadIdx.x == 0) {
    const uint g = blockIdx.x & 7;
    const uint a = atomicAdd(&bar[g * 32], 1u) + 1u;
    if (a == epoch * 8u) {                       // last of this group
      const uint bgl = atomicAdd(&bar[256], 1u) + 1u;
      if (bgl == epoch * 8u) {                   // last group overall
        __hip_atomic_store(&bar[288], epoch, __ATOMIC_RELEASE,
                           __HIP_MEMORY_SCOPE_AGENT);
      }
    }
    while (__hip_atomic_load(&bar[288], __ATOMIC_RELAXED,
                             __HIP_MEMORY_SCOPE_AGENT) < epoch)
      __builtin_amdgcn_s_sleep(1);
    __threadfence();          // acquire
  }
  __syncthreads();
}

// ---------------- K1: xz = x @ W + b (fp32, unchanged) ----------------
__global__ __launch_bounds__(256) void gemm_xz(
    const float* __restrict__ A, const float* __restrict__ W,
    const float* __restrict__ bias, float* __restrict__ C)
{
  __shared__ float As[16][68];
  __shared__ float Bs[16][68];
  const int tid = threadIdx.x;
  const int tx = tid & 15, ty = tid >> 4;
  const int n0 = blockIdx.x * 64, m0 = blockIdx.y * 64;
  const int ar = tid >> 2, ac = (tid & 3) << 2;
  const int br = tid >> 4, bc = (tid & 15) << 2;
  float acc[4][4] = {};
  for (int kt = 0; kt < Fn; kt += 16) {
    const float4 a4 = *(const float4*)(A + (size_t)(m0 + ar) * Fn + kt + ac);
    const float4 b4 = *(const float4*)(W + (size_t)(kt + br) * G4n + n0 + bc);
    __syncthreads();
    As[ac + 0][ar] = a4.x; As[ac + 1][ar] = a4.y;
    As[ac + 2][ar] = a4.z; As[ac + 3][ar] = a4.w;
    *(float4*)(&Bs[br][bc]) = b4;
    __syncthreads();
#pragma unroll
    for (int k = 0; k < 16; ++k) {
      const float4 av = *(const float4*)(&As[k][ty << 2]);
      const float4 bv = *(const float4*)(&Bs[k][tx << 2]);
      const float aarr[4] = {av.x, av.y, av.z, av.w};
      const float barr[4] = {bv.x, bv.y, bv.z, bv.w};
#pragma unroll
      for (int i = 0; i < 4; ++i)
#pragma unroll
        for (int j = 0; j < 4; ++j)
          acc[i][j] = fmaf(aarr[i], barr[j], acc[i][j]);
    }
  }
  const float4 bias4 = *(const float4*)(bias + n0 + (tx << 2));
  const float bb4[4] = {bias4.x, bias4.y, bias4.z, bias4.w};
#pragma unroll
  for (int i = 0; i < 4; ++i) {
    float4 ov;
    ov.x = acc[i][0] + bb4[0];
    ov.y = acc[i][1] + bb4[1];
    ov.z = acc[i][2] + bb4[2];
    ov.w = acc[i][3] + bb4[3];
    *(float4*)(C + (size_t)(m0 + (ty << 2) + i) * G4n + n0 + (tx << 2)) = ov;
  }
}

// ---------------- K2: MFMA LSTM recurrence (64 blocks x 8 waves) ----------------
// Block owns h-cols [8*blk, +8) as 2 col-groups of 4. Wave w: batch-tile
// mt = w&3 (16 batches), col-group cg = w>>2. A = U^T (static bf16 hi+lo in
// 128 VGPRs), B = h^T from packed global hfrag (double-buffered). C/D map
// (m89): lane(kg,n) reg r = z[gate r][hcol 8blk+4cg+kg][batch 16mt+n].
__global__ __launch_bounds__(512) void lstm_mfma(
    const float* __restrict__ xz, const float* __restrict__ U,
    float* __restrict__ h_seq, ushort* __restrict__ hfrag, uint* __restrict__ bar)
{
  const int tid = threadIdx.x;
  const int blk = blockIdx.x;       // 0..63
  const int w = tid >> 6;           // 0..7
  const int l = tid & 63;
  const int n = l & 15;             // B col = batch within tile; C/D col
  const int kg = l >> 4;            // k group; C/D row group
  const int mt = w & 3;             // batch tile
  const int cg = w >> 2;            // col-group within block

  // ---- one-time: U^T A-fragments (bf16 hi+lo split) ----
  // A[rho][k] = U[k][ugcol], ugcol = (rho&3)*512 + bc0 + (rho>>2); rho = n
  const int bc0 = (blk << 3) + (cg << 2);
  const int rho = n;
  const int ugcol = ((rho & 3) << 9) + bc0 + (rho >> 2);
  bf16x8 ufhi[16], uflo[16];
#pragma unroll
  for (int ks = 0; ks < 16; ++ks) {
    bf16x8 hi, lo;
#pragma unroll
    for (int e = 0; e < 8; ++e) {
      const float u = U[(size_t)(32 * ks + 8 * kg + e) * G4n + ugcol];
      const ushort uh = f2bf(u);
      hi[e] = (short)uh;
      lo[e] = (short)f2bf(u - bf2f(uh));
    }
    ufhi[ks] = hi; uflo[ks] = lo;
  }

  // zero hfrag buffer 0 (h_{-1}=0): 16384 uints over 32768 threads
  {
    const int gid = blk * 512 + tid;
    if (gid < 16384) ((uint*)hfrag)[gid] = 0u;
  }

  const int beta = (mt << 4) + n;         // batch this lane owns
  const int hc   = bc0 + kg;              // h-col this lane owns
  const float* xzb = xz + (size_t)beta * Tn * G4n + hc;  // + r*512 per gate
  float cst = 0.f;

  uint epoch = 1;
  gridbar(bar, epoch); ++epoch;           // hfrag[0] zeroed everywhere

  float xzc[4];
#pragma unroll
  for (int r = 0; r < 4; ++r) xzc[r] = xzb[r << 9];   // t = 0

  for (int t = 0; t < Tn; ++t) {
    const int cur = t & 1;
    float xzn[4];
    if (t + 1 < Tn) {
#pragma unroll
      for (int r = 0; r < 4; ++r) xzn[r] = xzb[(size_t)(t + 1) * G4n + (r << 9)];
    } else {
#pragma unroll
      for (int r = 0; r < 4; ++r) xzn[r] = 0.f;
    }

    // B-frags: lane holds B[k = 32*ks + 8*kg + e][col n] = h[16mt+n][k]
    const bf16x8* bbase = ((const bf16x8*)hfrag) + (size_t)cur * 4096 + mt * 1024 + l;
    f32x4 acch = {0.f, 0.f, 0.f, 0.f};
    f32x4 accl = {0.f, 0.f, 0.f, 0.f};
#pragma unroll
    for (int ks = 0; ks < 16; ++ks) {
      const bf16x8 bfr = bbase[ks * 64];
      acch = __builtin_amdgcn_mfma_f32_16x16x32_bf16(ufhi[ks], bfr, acch, 0, 0, 0);
      accl = __builtin_amdgcn_mfma_f32_16x16x32_bf16(uflo[ks], bfr, accl, 0, 0, 0);
    }

    // reg r = gate r (Keras i,f,g,o) for (batch beta, hcol hc)
    const float zi = acch[0] + accl[0] + xzc[0];
    const float zf = acch[1] + accl[1] + xzc[1];
    const float zg = acch[2] + accl[2] + xzc[2];
    const float zo = acch[3] + accl[3] + xzc[3];
    const float iv = 1.f / (1.f + expf(-zi));
    const float fv = 1.f / (1.f + expf(-zf));
    const float gv = tanhf(zg);
    const float ov = 1.f / (1.f + expf(-zo));
    cst = fv * cst + iv * gv;
    const float hv = ov * tanhf(cst);

    h_seq[((size_t)beta * Tn + t) * Hn + hc] = hv;
    {
      const int ks2 = hc >> 5, sub = (hc & 31) >> 3, j8 = hc & 7;
      hfrag[(size_t)(cur ^ 1) * 32768 +
            (((mt * 16 + ks2) * 64) + sub * 16 + (beta & 15)) * 8 + j8] = f2bf(hv);
    }
#pragma unroll
    for (int r = 0; r < 4; ++r) xzc[r] = xzn[r];
    gridbar(bar, epoch); ++epoch;        // h_t visible device-wide
  }
}

// ---------------- K3: out = h_seq @ Wd + bd (unchanged) ----------------
__global__ __launch_bounds__(256) void proj_out(
    const float* __restrict__ h_seq, const float* __restrict__ Wd,
    const float* __restrict__ bd, float* __restrict__ out)
{
  __shared__ float Wdt[10][516];
  for (int i = threadIdx.x; i < Hn * On; i += 256) {
    const int k = i / 10, o = i - k * 10;
    Wdt[o][k] = Wd[i];
  }
  __syncthreads();
  const int idx = blockIdx.x * 256 + threadIdx.x;
  const int row = idx / 10, o = idx - row * 10;
  const float* hp = h_seq + (size_t)row * Hn;
  const float* wp = &Wdt[o][0];
  float acc = bd[o];
#pragma unroll 4
  for (int k = 0; k < Hn; k += 4) {
    const float4 h4 = *(const float4*)(hp + k);
    const float4 w4 = *(const float4*)(wp + k);
    acc = fmaf(h4.x, w4.x, acc);
    acc = fmaf(h4.y, w4.y, acc);
    acc = fmaf(h4.z, w4.z, acc);
    acc = fmaf(h4.w, w4.w, acc);
  }
  out[idx] = acc;
}

extern "C" void kernel_launch(void* const* d_in, const int* in_sizes, int n_in,
                              void* d_out, int out_size, void* d_ws, size_t ws_size,
                              hipStream_t stream)
{
  const float* x  = (const float*)d_in[0];
  const float* W  = (const float*)d_in[1];
  const float* U  = (const float*)d_in[2];
  const float* b  = (const float*)d_in[3];
  const float* Wd = (const float*)d_in[4];
  const float* bd = (const float*)d_in[5];
  float* out = (float*)d_out;

  float* xz     = (float*)d_ws;
  float* h_seq  = xz + XZ_ELEMS;
  ushort* hfrag = (ushort*)(h_seq + HSEQ_ELEMS);
  uint* bar     = (uint*)(hfrag + 2 * 32768);

  gemm_xz<<<dim3(G4n / 64, (Bn * Tn) / 64), 256, 0, stream>>>(x, W, b, xz);

  hipMemsetAsync(bar, 0, 512 * sizeof(uint), stream);   // barrier state = 0
  lstm_mfma<<<dim3(NBLK), dim3(512), 0, stream>>>(xz, U, h_seq, hfrag, bar);

  proj_out<<<(Bn * Tn * On) / 256, 256, 0, stream>>>(h_seq, Wd, bd, out);
}

// Round 7
// 3231.668 us; speedup vs baseline: 7.6492x; 3.0836x over previous
//
#include <hip/hip_runtime.h>
#include <cmath>

typedef __attribute__((ext_vector_type(8))) short bf16x8;
typedef __attribute__((ext_vector_type(4))) float f32x4;

static constexpr int Bn = 64, Tn = 512, Fn = 784, Hn = 512, G4n = 2048, On = 10;
static constexpr int NBLK = 64;                            // 64 blocks x 512 thr
static constexpr long XZ_ELEMS   = (long)Bn * Tn * G4n;    // 256 MB (xzT layout)
static constexpr long HSEQ_ELEMS = (long)Bn * Tn * Hn;     // 64 MB
// ws: xzT f32 [t][gcol][beta] | h_seq f32 [beta][t][hc] | hfrag 2x32768 ushort | flags 64x32 uint

__device__ __forceinline__ ushort f2bf(float x) {   // RNE fp32->bf16
  uint b = __float_as_uint(x);
  uint r = (b + 0x7FFFu + ((b >> 16) & 1u)) >> 16;
  return (ushort)r;
}
__device__ __forceinline__ float bf2f(ushort h) {
  return __uint_as_float(((uint)h) << 16);
}

// ---------------- K1: xzT = (x @ W + b) transposed ----------------
// Block = (one t, all 64 betas) x 64 gcols. acc[i][j]: i = beta-sub, j = gcol-sub.
// acc columns are beta-contiguous -> transposed store is free float4s.
__global__ __launch_bounds__(256) void gemm_xz(
    const float* __restrict__ A, const float* __restrict__ W,
    const float* __restrict__ bias, float* __restrict__ xzT)
{
  __shared__ float As[16][68];
  __shared__ float Bs[16][68];
  const int tid = threadIdx.x;
  const int tx = tid & 15, ty = tid >> 4;
  const int g0 = blockIdx.x * 64;          // gcol tile
  const int tt = blockIdx.y;               // timestep
  const int ar = tid >> 2, ac = (tid & 3) << 2;   // A: 64 betas x 16k
  const int br = tid >> 4, bc = (tid & 15) << 2;  // W: 16k x 64 gcols
  float acc[4][4] = {};
  for (int kt = 0; kt < Fn; kt += 16) {
    const float4 a4 = *(const float4*)(A + ((size_t)ar * Tn + tt) * Fn + kt + ac);
    const float4 b4 = *(const float4*)(W + (size_t)(kt + br) * G4n + g0 + bc);
    __syncthreads();
    As[ac + 0][ar] = a4.x; As[ac + 1][ar] = a4.y;
    As[ac + 2][ar] = a4.z; As[ac + 3][ar] = a4.w;
    *(float4*)(&Bs[br][bc]) = b4;
    __syncthreads();
#pragma unroll
    for (int k = 0; k < 16; ++k) {
      const float4 av = *(const float4*)(&As[k][ty << 2]);
      const float4 bv = *(const float4*)(&Bs[k][tx << 2]);
      const float aarr[4] = {av.x, av.y, av.z, av.w};
      const float barr[4] = {bv.x, bv.y, bv.z, bv.w};
#pragma unroll
      for (int i = 0; i < 4; ++i)
#pragma unroll
        for (int j = 0; j < 4; ++j)
          acc[i][j] = fmaf(aarr[i], barr[j], acc[i][j]);
    }
  }
#pragma unroll
  for (int j = 0; j < 4; ++j) {
    const int gcol = g0 + (tx << 2) + j;
    const float bb = bias[gcol];
    float4 ov;
    ov.x = acc[0][j] + bb;
    ov.y = acc[1][j] + bb;
    ov.z = acc[2][j] + bb;
    ov.w = acc[3][j] + bb;
    *(float4*)(xzT + ((size_t)tt * G4n + gcol) * Bn + (ty << 2)) = ov;
  }
}

// ---------------- K2: MFMA LSTM recurrence (fence-free, sc1 exchange) ----------------
// 64 blocks x 512 thr. Wave w: mt = w&3 (16 batches), cg = w>>2. Block owns
// h-cols [8*blk, +8). U^T static in regs (bf16 hi+lo). h exchanged via global
// hfrag in B-frag layout using agent-scope (sc1, L2-bypass) atomics -> no
// __threadfence / L2 flush anywhere. Per step: stage hfrag -> LDS (coalesced),
// MFMA, gates, sc1 stores, vmcnt-drain, flag barrier (all-to-all poll).
__global__ __launch_bounds__(512) void lstm_mfma(
    const float* __restrict__ xzT, const float* __restrict__ U,
    float* __restrict__ h_seq, uint* __restrict__ hfrag_u, uint* __restrict__ flags)
{
  __shared__ uint hsm[16384];   // 64 KB: current h in B-frag layout
  const int tid = threadIdx.x;
  const int blk = blockIdx.x;       // 0..63
  const int w = tid >> 6;           // 0..7
  const int l = tid & 63;
  const int n = l & 15;             // B col = batch within tile; C/D col
  const int kg = l >> 4;            // k group; C/D row group
  const int mt = w & 3;             // batch tile
  const int cg = w >> 2;            // col-group within block

  // ---- one-time: U^T A-fragments (bf16 hi+lo split) ----
  const int bc0 = (blk << 3) + (cg << 2);
  const int rho = n;
  const int ugcol = ((rho & 3) << 9) + bc0 + (rho >> 2);
  bf16x8 ufhi[16], uflo[16];
#pragma unroll
  for (int ks = 0; ks < 16; ++ks) {
    bf16x8 hi, lo;
#pragma unroll
    for (int e = 0; e < 8; ++e) {
      const float u = U[(size_t)(32 * ks + 8 * kg + e) * G4n + ugcol];
      const ushort uh = f2bf(u);
      hi[e] = (short)uh;
      lo[e] = (short)f2bf(u - bf2f(uh));
    }
    ufhi[ks] = hi; uflo[ks] = lo;
  }

  const int beta = (mt << 4) + n;         // batch this lane owns
  const int hc   = bc0 + kg;              // h-col this lane owns
  float cst = 0.f;

  // hfrag store slot (uint-packed pairs; lanes kg even store self|partner)
  const uint sidx16 = ((uint)((mt * 16 + (blk >> 2)) * 64 + (blk & 3) * 16 + n) << 3)
                      + (uint)((cg << 2) + kg);

  // xz for t=0 (plain loads; xzT ready by stream order)
  float xzc[4];
#pragma unroll
  for (int r = 0; r < 4; ++r)
    xzc[r] = xzT[((size_t)0 * G4n + (r << 9) + hc) * Bn + beta];

  uint epoch = 1;
  for (int t = 0; t < Tn; ++t) {
    const int cur = t & 1;

    // ---- stage hfrag[cur] (64 KB) into LDS: coalesced sc1 loads ----
    {
      const uint base = (uint)cur * 16384u + (uint)tid;
      uint tmp[32];
#pragma unroll
      for (int i = 0; i < 32; ++i)
        tmp[i] = __hip_atomic_load(&hfrag_u[base + (uint)(i << 9)],
                                   __ATOMIC_RELAXED, __HIP_MEMORY_SCOPE_AGENT);
#pragma unroll
      for (int i = 0; i < 32; ++i)
        hsm[tid + (i << 9)] = tmp[i];
    }
    __syncthreads();

    // ---- MFMA: z^T = U^T (A, static) x h^T (B, from LDS) ----
    const bf16x8* bb = ((const bf16x8*)hsm) + mt * 1024 + l;
    f32x4 acch = {0.f, 0.f, 0.f, 0.f};
    f32x4 accl = {0.f, 0.f, 0.f, 0.f};
#pragma unroll
    for (int ks = 0; ks < 16; ++ks) {
      const bf16x8 bfr = bb[ks * 64];
      acch = __builtin_amdgcn_mfma_f32_16x16x32_bf16(ufhi[ks], bfr, acch, 0, 0, 0);
      accl = __builtin_amdgcn_mfma_f32_16x16x32_bf16(uflo[ks], bfr, accl, 0, 0, 0);
    }

    // reg r = gate r (Keras i,f,g,o) for (batch beta, hcol hc)
    const float zi = acch[0] + accl[0] + xzc[0];
    const float zf = acch[1] + accl[1] + xzc[1];
    const float zg = acch[2] + accl[2] + xzc[2];
    const float zo = acch[3] + accl[3] + xzc[3];
    const float iv = 1.f / (1.f + expf(-zi));
    const float fv = 1.f / (1.f + expf(-zf));
    const float gv = tanhf(zg);
    const float ov = 1.f / (1.f + expf(-zo));
    cst = fv * cst + iv * gv;
    const float hv = ov * tanhf(cst);

    // h_seq: plain cached store (visible to proj_out at kernel end)
    h_seq[((size_t)beta * Tn + t) * Hn + hc] = hv;

    // hfrag[cur^1]: agent-scope packed-uint stores (L2-bypass)
    const uint myv = (uint)f2bf(hv);
    const uint pv = (uint)__shfl_xor((int)myv, 16, 64);   // partner kg^1 (all lanes exec)
    if ((kg & 1) == 0) {
      const uint comb = myv | (pv << 16);
      __hip_atomic_store(&hfrag_u[(uint)(cur ^ 1) * 16384u + (sidx16 >> 1)], comb,
                         __ATOMIC_RELAXED, __HIP_MEMORY_SCOPE_AGENT);
    }

    // ---- release: drain this wave's stores, then block-wide join ----
    asm volatile("s_waitcnt vmcnt(0)" ::: "memory");
    __syncthreads();
    if (tid == 0)
      __hip_atomic_store(&flags[blk << 5], epoch,
                         __ATOMIC_RELAXED, __HIP_MEMORY_SCOPE_AGENT);

    // prefetch next step's xz (overlaps the spin below)
    if (t + 1 < Tn) {
#pragma unroll
      for (int r = 0; r < 4; ++r)
        xzc[r] = xzT[((size_t)(t + 1) * G4n + (r << 9) + hc) * Bn + beta];
    }

    // ---- all-to-all barrier: wave 0 polls all 64 flags in parallel ----
    if (tid < 64) {
      while (1) {
        const uint f = __hip_atomic_load(&flags[l << 5],
                                         __ATOMIC_RELAXED, __HIP_MEMORY_SCOPE_AGENT);
        if (__all(f >= epoch)) break;
        __builtin_amdgcn_s_sleep(1);
      }
    }
    __syncthreads();   // all waves: h_t globally visible; hsm safe to overwrite
    ++epoch;
  }
}

// ---------------- K3: out = h_seq @ Wd + bd (unchanged) ----------------
__global__ __launch_bounds__(256) void proj_out(
    const float* __restrict__ h_seq, const float* __restrict__ Wd,
    const float* __restrict__ bd, float* __restrict__ out)
{
  __shared__ float Wdt[10][516];
  for (int i = threadIdx.x; i < Hn * On; i += 256) {
    const int k = i / 10, o = i - k * 10;
    Wdt[o][k] = Wd[i];
  }
  __syncthreads();
  const int idx = blockIdx.x * 256 + threadIdx.x;
  const int row = idx / 10, o = idx - row * 10;
  const float* hp = h_seq + (size_t)row * Hn;
  const float* wp = &Wdt[o][0];
  float acc = bd[o];
#pragma unroll 4
  for (int k = 0; k < Hn; k += 4) {
    const float4 h4 = *(const float4*)(hp + k);
    const float4 w4 = *(const float4*)(wp + k);
    acc = fmaf(h4.x, w4.x, acc);
    acc = fmaf(h4.y, w4.y, acc);
    acc = fmaf(h4.z, w4.z, acc);
    acc = fmaf(h4.w, w4.w, acc);
  }
  out[idx] = acc;
}

extern "C" void kernel_launch(void* const* d_in, const int* in_sizes, int n_in,
                              void* d_out, int out_size, void* d_ws, size_t ws_size,
                              hipStream_t stream)
{
  const float* x  = (const float*)d_in[0];
  const float* W  = (const float*)d_in[1];
  const float* U  = (const float*)d_in[2];
  const float* b  = (const float*)d_in[3];
  const float* Wd = (const float*)d_in[4];
  const float* bd = (const float*)d_in[5];
  float* out = (float*)d_out;

  float* xzT    = (float*)d_ws;
  float* h_seq  = xzT + XZ_ELEMS;
  uint* hfrag_u = (uint*)(h_seq + HSEQ_ELEMS);      // 2 x 16384 uints (128 KB)
  uint* flags   = hfrag_u + 2 * 16384;              // 64 x 32 uints (8 KB)

  gemm_xz<<<dim3(G4n / 64, Tn), 256, 0, stream>>>(x, W, b, xzT);

  // zero hfrag (h_{-1}=0) + flags in one captured memset (136 KB)
  hipMemsetAsync(hfrag_u, 0, (2 * 16384 + 64 * 32) * sizeof(uint), stream);
  lstm_mfma<<<dim3(NBLK), dim3(512), 0, stream>>>(xzT, U, h_seq, hfrag_u, flags);

  proj_out<<<(Bn * Tn * On) / 256, 256, 0, stream>>>(h_seq, Wd, bd, out);
}

// Round 9
// 2484.319 us; speedup vs baseline: 9.9503x; 1.3008x over previous
//
#include <hip/hip_runtime.h>
#include <cmath>

typedef __attribute__((ext_vector_type(8))) short bf16x8;
typedef __attribute__((ext_vector_type(8))) ushort u16x8;
typedef __attribute__((ext_vector_type(4))) float f32x4;

static constexpr int Bn = 64, Tn = 512, Fn = 784, Hn = 512, G4n = 2048, On = 10;
static constexpr int NBLK = 64;
static constexpr int KP = 800;                             // 784 padded to 25*32
static constexpr long XZ_ELEMS   = (long)Bn * Tn * G4n;    // 256 MB
static constexpr long HSEQ_ELEMS = (long)Bn * Tn * Hn;     // 64 MB
static constexpr size_t BASE_END = (size_t)XZ_ELEMS * 4 + (size_t)HSEQ_ELEMS * 4
                                 + 2 * 16384 * 4 + 64 * 32 * 4;     // 335,683,584
static constexpr size_t MFMA_END = BASE_END + (size_t)32768 * KP * 2
                                 + 2 * (size_t)G4n * KP * 2;        // 394,665,984

__device__ __forceinline__ ushort f2bf(float x) {   // RNE fp32->bf16
  uint b = __float_as_uint(x);
  uint r = (b + 0x7FFFu + ((b >> 16) & 1u)) >> 16;
  return (ushort)r;
}
__device__ __forceinline__ float bf2f(ushort h) {
  return __uint_as_float(((uint)h) << 16);
}

// ---------------- P1: x [32768][784] f32 -> xhi/xlo [32768][800] bf16 ----------------
__global__ __launch_bounds__(256) void cvt_x(
    const float* __restrict__ x, ushort* __restrict__ xhi, ushort* __restrict__ xlo)
{
  const int idx = blockIdx.x * 256 + threadIdx.x;   // 32768*100
  const int m = idx / 100, kc = idx - m * 100;
  u16x8 h = {0,0,0,0,0,0,0,0}, lo = {0,0,0,0,0,0,0,0};
  if (kc < 98) {   // 784 = 98*8 exactly
    const float4 v0 = *(const float4*)(x + (size_t)m * Fn + kc * 8);
    const float4 v1 = *(const float4*)(x + (size_t)m * Fn + kc * 8 + 4);
    const float vv[8] = {v0.x, v0.y, v0.z, v0.w, v1.x, v1.y, v1.z, v1.w};
#pragma unroll
    for (int e = 0; e < 8; ++e) {
      const ushort hh = f2bf(vv[e]);
      h[e] = hh;
      lo[e] = f2bf(vv[e] - bf2f(hh));
    }
  }
  *(u16x8*)(xhi + (size_t)m * KP + kc * 8) = h;
  *(u16x8*)(xlo + (size_t)m * KP + kc * 8) = lo;
}

// ---------------- P2: W [784][2048] f32 -> WThi/WTlo [2048][800] bf16 ----------------
__global__ __launch_bounds__(256) void cvt_w(
    const float* __restrict__ W, ushort* __restrict__ WThi, ushort* __restrict__ WTlo)
{
  const int idx = blockIdx.x * 256 + threadIdx.x;   // 100*2048
  const int kc = idx >> 11, gcol = idx & 2047;
  u16x8 h = {0,0,0,0,0,0,0,0}, lo = {0,0,0,0,0,0,0,0};
#pragma unroll
  for (int e = 0; e < 8; ++e) {
    const int k = kc * 8 + e;
    if (k < Fn) {
      const float v = W[(size_t)k * G4n + gcol];
      const ushort hh = f2bf(v);
      h[e] = hh;
      lo[e] = f2bf(v - bf2f(hh));
    }
  }
  *(u16x8*)(WThi + (size_t)gcol * KP + kc * 8) = h;
  *(u16x8*)(WTlo + (size_t)gcol * KP + kc * 8) = lo;
}

// ---------------- K1: xzT[t][gcol][beta] = (x@W+b)^T via MFMA, 3-term bf16 split ----
// FIXED vs R8: wave columns = 16 BETAS (n) x 4 t (bj), since m = beta*512 + t.
// A = WT rows (gcols, consecutive, coalesced). B cols = betas -> per-lane row
// gather (stride-512 rows, L3-resident x). C store lane-contiguous in beta:
// 4 x 64B segments per store instr, fully coalesced into [t][gcol][beta].
// bid: gt (16) | bgh (2) | t0 (128). Block: 128 gcol x (32 beta x 4 t).
__global__ __launch_bounds__(256, 2) void gemm_xz_mfma(
    const ushort* __restrict__ WThi, const ushort* __restrict__ WTlo,
    const ushort* __restrict__ xhi,  const ushort* __restrict__ xlo,
    const float* __restrict__ bias, float* __restrict__ xzT)
{
  const int tid = threadIdx.x;
  const int wv = tid >> 6, l = tid & 63;
  const int wr = wv >> 1, wc = wv & 1;
  const int gt  = blockIdx.x & 15;
  const int bgh = (blockIdx.x >> 4) & 1;
  const int t0  = blockIdx.x >> 5;
  const int g0 = gt * 128 + wr * 64;
  const int bg0 = bgh * 32 + wc * 16;
  const int t_base = t0 * 4;
  const int n = l & 15, kg = l >> 4;

  const ushort* pah = WThi + (size_t)(g0 + n) * KP + kg * 8;
  const ushort* pal = WTlo + (size_t)(g0 + n) * KP + kg * 8;
  // B rows: m(n, bj) = (bg0 + n)*512 + t_base + bj
  const size_t mrow = ((size_t)(bg0 + n) * Tn + t_base) * KP + kg * 8;
  const ushort* pbh = xhi + mrow;
  const ushort* pbl = xlo + mrow;

  f32x4 acc[4][4] = {};
  for (int ks = 0; ks < 25; ++ks) {
    bf16x8 ah[4], al[4], bh[4], bl[4];
#pragma unroll
    for (int i = 0; i < 4; ++i) {
      const size_t ao = (size_t)i * 16 * KP + ks * 32;   // gcol group stride
      ah[i] = *(const bf16x8*)(pah + ao);
      al[i] = *(const bf16x8*)(pal + ao);
      const size_t bo = (size_t)i * KP + ks * 32;        // t (bj) stride = 1 row
      bh[i] = *(const bf16x8*)(pbh + bo);
      bl[i] = *(const bf16x8*)(pbl + bo);
    }
#pragma unroll
    for (int ai = 0; ai < 4; ++ai)
#pragma unroll
      for (int bj = 0; bj < 4; ++bj) {
        acc[ai][bj] = __builtin_amdgcn_mfma_f32_16x16x32_bf16(ah[ai], bh[bj], acc[ai][bj], 0, 0, 0);
        acc[ai][bj] = __builtin_amdgcn_mfma_f32_16x16x32_bf16(ah[ai], bl[bj], acc[ai][bj], 0, 0, 0);
        acc[ai][bj] = __builtin_amdgcn_mfma_f32_16x16x32_bf16(al[ai], bh[bj], acc[ai][bj], 0, 0, 0);
      }
  }
  // C row = gcol = g0 + ai*16 + kg*4 + r ; col -> beta = bg0 + n, t = t_base + bj
#pragma unroll
  for (int ai = 0; ai < 4; ++ai) {
#pragma unroll
    for (int r = 0; r < 4; ++r) {
      const int gc = g0 + ai * 16 + (kg << 2) + r;
      const float bb = bias[gc];
#pragma unroll
      for (int bj = 0; bj < 4; ++bj)
        xzT[((size_t)(t_base + bj) * G4n + gc) * Bn + bg0 + n] = acc[ai][bj][r] + bb;
    }
  }
}

// ---------------- K1-fallback: fp32 tiled (R7 version) ----------------
__global__ __launch_bounds__(256) void gemm_xz_f32(
    const float* __restrict__ A, const float* __restrict__ W,
    const float* __restrict__ bias, float* __restrict__ xzT)
{
  __shared__ float As[16][68];
  __shared__ float Bs[16][68];
  const int tid = threadIdx.x;
  const int tx = tid & 15, ty = tid >> 4;
  const int g0 = blockIdx.x * 64;
  const int tt = blockIdx.y;
  const int ar = tid >> 2, ac = (tid & 3) << 2;
  const int br = tid >> 4, bc = (tid & 15) << 2;
  float acc[4][4] = {};
  for (int kt = 0; kt < Fn; kt += 16) {
    const float4 a4 = *(const float4*)(A + ((size_t)ar * Tn + tt) * Fn + kt + ac);
    const float4 b4 = *(const float4*)(W + (size_t)(kt + br) * G4n + g0 + bc);
    __syncthreads();
    As[ac + 0][ar] = a4.x; As[ac + 1][ar] = a4.y;
    As[ac + 2][ar] = a4.z; As[ac + 3][ar] = a4.w;
    *(float4*)(&Bs[br][bc]) = b4;
    __syncthreads();
#pragma unroll
    for (int k = 0; k < 16; ++k) {
      const float4 av = *(const float4*)(&As[k][ty << 2]);
      const float4 bv = *(const float4*)(&Bs[k][tx << 2]);
      const float aarr[4] = {av.x, av.y, av.z, av.w};
      const float barr[4] = {bv.x, bv.y, bv.z, bv.w};
#pragma unroll
      for (int i = 0; i < 4; ++i)
#pragma unroll
        for (int j = 0; j < 4; ++j)
          acc[i][j] = fmaf(aarr[i], barr[j], acc[i][j]);
    }
  }
#pragma unroll
  for (int j = 0; j < 4; ++j) {
    const int gcol = g0 + (tx << 2) + j;
    const float bb = bias[gcol];
    float4 ov;
    ov.x = acc[0][j] + bb;
    ov.y = acc[1][j] + bb;
    ov.z = acc[2][j] + bb;
    ov.w = acc[3][j] + bb;
    *(float4*)(xzT + ((size_t)tt * G4n + gcol) * Bn + (ty << 2)) = ov;
  }
}

// ---------------- K2: MFMA LSTM recurrence (R7 proven version, verbatim) ----------------
__global__ __launch_bounds__(512) void lstm_mfma(
    const float* __restrict__ xzT, const float* __restrict__ U,
    float* __restrict__ h_seq, uint* __restrict__ hfrag_u, uint* __restrict__ flags)
{
  __shared__ uint hsm[16384];   // 64 KB: current h in B-frag layout
  const int tid = threadIdx.x;
  const int blk = blockIdx.x;       // 0..63
  const int w = tid >> 6;           // 0..7
  const int l = tid & 63;
  const int n = l & 15;             // B col = batch within tile; C/D col
  const int kg = l >> 4;            // k group; C/D row group
  const int mt = w & 3;             // batch tile
  const int cg = w >> 2;            // col-group within block

  // ---- one-time: U^T A-fragments (bf16 hi+lo split) ----
  const int bc0 = (blk << 3) + (cg << 2);
  const int rho = n;
  const int ugcol = ((rho & 3) << 9) + bc0 + (rho >> 2);
  bf16x8 ufhi[16], uflo[16];
#pragma unroll
  for (int ks = 0; ks < 16; ++ks) {
    bf16x8 hi, lo;
#pragma unroll
    for (int e = 0; e < 8; ++e) {
      const float u = U[(size_t)(32 * ks + 8 * kg + e) * G4n + ugcol];
      const ushort uh = f2bf(u);
      hi[e] = (short)uh;
      lo[e] = (short)f2bf(u - bf2f(uh));
    }
    ufhi[ks] = hi; uflo[ks] = lo;
  }

  const int beta = (mt << 4) + n;         // batch this lane owns
  const int hc   = bc0 + kg;              // h-col this lane owns
  float cst = 0.f;

  const uint sidx16 = ((uint)((mt * 16 + (blk >> 2)) * 64 + (blk & 3) * 16 + n) << 3)
                      + (uint)((cg << 2) + kg);

  float xzc[4];
#pragma unroll
  for (int r = 0; r < 4; ++r)
    xzc[r] = xzT[((size_t)0 * G4n + (r << 9) + hc) * Bn + beta];

  uint epoch = 1;
  for (int t = 0; t < Tn; ++t) {
    const int cur = t & 1;

    // ---- stage hfrag[cur] (64 KB) into LDS: coalesced sc1 loads ----
    {
      const uint base = (uint)cur * 16384u + (uint)tid;
      uint tmp[32];
#pragma unroll
      for (int i = 0; i < 32; ++i)
        tmp[i] = __hip_atomic_load(&hfrag_u[base + (uint)(i << 9)],
                                   __ATOMIC_RELAXED, __HIP_MEMORY_SCOPE_AGENT);
#pragma unroll
      for (int i = 0; i < 32; ++i)
        hsm[tid + (i << 9)] = tmp[i];
    }
    __syncthreads();

    // ---- MFMA: z^T = U^T (A, static) x h^T (B, from LDS) ----
    const bf16x8* bb = ((const bf16x8*)hsm) + mt * 1024 + l;
    f32x4 acch = {0.f, 0.f, 0.f, 0.f};
    f32x4 accl = {0.f, 0.f, 0.f, 0.f};
#pragma unroll
    for (int ks = 0; ks < 16; ++ks) {
      const bf16x8 bfr = bb[ks * 64];
      acch = __builtin_amdgcn_mfma_f32_16x16x32_bf16(ufhi[ks], bfr, acch, 0, 0, 0);
      accl = __builtin_amdgcn_mfma_f32_16x16x32_bf16(uflo[ks], bfr, accl, 0, 0, 0);
    }

    // reg r = gate r (Keras i,f,g,o) for (batch beta, hcol hc)
    const float zi = acch[0] + accl[0] + xzc[0];
    const float zf = acch[1] + accl[1] + xzc[1];
    const float zg = acch[2] + accl[2] + xzc[2];
    const float zo = acch[3] + accl[3] + xzc[3];
    const float iv = 1.f / (1.f + expf(-zi));
    const float fv = 1.f / (1.f + expf(-zf));
    const float gv = tanhf(zg);
    const float ov = 1.f / (1.f + expf(-zo));
    cst = fv * cst + iv * gv;
    const float hv = ov * tanhf(cst);

    h_seq[((size_t)beta * Tn + t) * Hn + hc] = hv;

    const uint myv = (uint)f2bf(hv);
    const uint pv = (uint)__shfl_xor((int)myv, 16, 64);   // partner kg^1
    if ((kg & 1) == 0) {
      const uint comb = myv | (pv << 16);
      __hip_atomic_store(&hfrag_u[(uint)(cur ^ 1) * 16384u + (sidx16 >> 1)], comb,
                         __ATOMIC_RELAXED, __HIP_MEMORY_SCOPE_AGENT);
    }

    // ---- release: drain this wave's stores, then block-wide join ----
    asm volatile("s_waitcnt vmcnt(0)" ::: "memory");
    __syncthreads();
    if (tid == 0)
      __hip_atomic_store(&flags[blk << 5], epoch,
                         __ATOMIC_RELAXED, __HIP_MEMORY_SCOPE_AGENT);

    // prefetch next step's xz (overlaps the spin below)
    if (t + 1 < Tn) {
#pragma unroll
      for (int r = 0; r < 4; ++r)
        xzc[r] = xzT[((size_t)(t + 1) * G4n + (r << 9) + hc) * Bn + beta];
    }

    // ---- all-to-all barrier: wave 0 polls all 64 flags in parallel ----
    if (tid < 64) {
      while (1) {
        const uint f = __hip_atomic_load(&flags[l << 5],
                                         __ATOMIC_RELAXED, __HIP_MEMORY_SCOPE_AGENT);
        if (__all(f >= epoch)) break;
        __builtin_amdgcn_s_sleep(1);
      }
    }
    __syncthreads();
    ++epoch;
  }
}

// ---------------- K3: out = h_seq @ Wd + bd ----------------
__global__ __launch_bounds__(256) void proj_out(
    const float* __restrict__ h_seq, const float* __restrict__ Wd,
    const float* __restrict__ bd, float* __restrict__ out)
{
  __shared__ float Wdt[10][516];
  for (int i = threadIdx.x; i < Hn * On; i += 256) {
    const int k = i / 10, o = i - k * 10;
    Wdt[o][k] = Wd[i];
  }
  __syncthreads();
  const int idx = blockIdx.x * 256 + threadIdx.x;
  const int row = idx / 10, o = idx - row * 10;
  const float* hp = h_seq + (size_t)row * Hn;
  const float* wp = &Wdt[o][0];
  float acc = bd[o];
#pragma unroll 4
  for (int k = 0; k < Hn; k += 4) {
    const float4 h4 = *(const float4*)(hp + k);
    const float4 w4 = *(const float4*)(wp + k);
    acc = fmaf(h4.x, w4.x, acc);
    acc = fmaf(h4.y, w4.y, acc);
    acc = fmaf(h4.z, w4.z, acc);
    acc = fmaf(h4.w, w4.w, acc);
  }
  out[idx] = acc;
}

extern "C" void kernel_launch(void* const* d_in, const int* in_sizes, int n_in,
                              void* d_out, int out_size, void* d_ws, size_t ws_size,
                              hipStream_t stream)
{
  const float* x  = (const float*)d_in[0];
  const float* W  = (const float*)d_in[1];
  const float* U  = (const float*)d_in[2];
  const float* b  = (const float*)d_in[3];
  const float* Wd = (const float*)d_in[4];
  const float* bd = (const float*)d_in[5];
  float* out = (float*)d_out;

  float* xzT    = (float*)d_ws;
  float* h_seq  = xzT + XZ_ELEMS;
  uint* hfrag_u = (uint*)(h_seq + HSEQ_ELEMS);
  uint* flags   = hfrag_u + 2 * 16384;
  // bf16 split arrays: xhi overlaps h_seq (dead until lstm); rest past BASE_END
  ushort* xhi  = (ushort*)h_seq;
  ushort* xlo  = (ushort*)((char*)d_ws + BASE_END);
  ushort* WThi = xlo + (size_t)32768 * KP;
  ushort* WTlo = WThi + (size_t)G4n * KP;

  if (ws_size >= MFMA_END) {
    cvt_x<<<12800, 256, 0, stream>>>(x, xhi, xlo);
    cvt_w<<<800, 256, 0, stream>>>(W, WThi, WTlo);
    gemm_xz_mfma<<<4096, 256, 0, stream>>>(WThi, WTlo, xhi, xlo, b, xzT);
  } else {
    gemm_xz_f32<<<dim3(G4n / 64, Tn), 256, 0, stream>>>(x, W, b, xzT);
  }

  hipMemsetAsync(hfrag_u, 0, (2 * 16384 + 64 * 32) * sizeof(uint), stream);
  lstm_mfma<<<dim3(NBLK), dim3(512), 0, stream>>>(xzT, U, h_seq, hfrag_u, flags);

  proj_out<<<(Bn * Tn * On) / 256, 256, 0, stream>>>(h_seq, Wd, bd, out);
}

// Round 10
// 2337.463 us; speedup vs baseline: 10.5754x; 1.0628x over previous
//
#include <hip/hip_runtime.h>
#include <cmath>

typedef __attribute__((ext_vector_type(8))) short bf16x8;
typedef __attribute__((ext_vector_type(8))) ushort u16x8;
typedef __attribute__((ext_vector_type(4))) float f32x4;

static constexpr int Bn = 64, Tn = 512, Fn = 784, Hn = 512, G4n = 2048, On = 10;
static constexpr int NBLK = 64;
static constexpr int KP = 800;                             // 784 padded to 25*32
static constexpr long XZ_ELEMS   = (long)Bn * Tn * G4n;    // 256 MB
static constexpr long HSEQ_ELEMS = (long)Bn * Tn * Hn;     // 64 MB
// hfrag: 2 buffers x 4 clusters x 8192 tagged uints = 65536 uints (256 KB)
static constexpr size_t BASE_END = (size_t)XZ_ELEMS * 4 + (size_t)HSEQ_ELEMS * 4
                                 + (size_t)65536 * 4;               // 335,806,464
static constexpr size_t MFMA_END = BASE_END + (size_t)32768 * KP * 2
                                 + 2 * (size_t)G4n * KP * 2;        // 394,788,864

__device__ __forceinline__ ushort f2bf(float x) {   // RNE fp32->bf16
  uint b = __float_as_uint(x);
  uint r = (b + 0x7FFFu + ((b >> 16) & 1u)) >> 16;
  return (ushort)r;
}
__device__ __forceinline__ float bf2f(ushort h) {
  return __uint_as_float(((uint)h) << 16);
}

// ---------------- P1: x [32768][784] f32 -> xhi/xlo [32768][800] bf16 ----------------
__global__ __launch_bounds__(256) void cvt_x(
    const float* __restrict__ x, ushort* __restrict__ xhi, ushort* __restrict__ xlo)
{
  const int idx = blockIdx.x * 256 + threadIdx.x;   // 32768*100
  const int m = idx / 100, kc = idx - m * 100;
  u16x8 h = {0,0,0,0,0,0,0,0}, lo = {0,0,0,0,0,0,0,0};
  if (kc < 98) {   // 784 = 98*8 exactly
    const float4 v0 = *(const float4*)(x + (size_t)m * Fn + kc * 8);
    const float4 v1 = *(const float4*)(x + (size_t)m * Fn + kc * 8 + 4);
    const float vv[8] = {v0.x, v0.y, v0.z, v0.w, v1.x, v1.y, v1.z, v1.w};
#pragma unroll
    for (int e = 0; e < 8; ++e) {
      const ushort hh = f2bf(vv[e]);
      h[e] = hh;
      lo[e] = f2bf(vv[e] - bf2f(hh));
    }
  }
  *(u16x8*)(xhi + (size_t)m * KP + kc * 8) = h;
  *(u16x8*)(xlo + (size_t)m * KP + kc * 8) = lo;
}

// ---------------- P2: W [784][2048] f32 -> WThi/WTlo [2048][800] bf16 ----------------
__global__ __launch_bounds__(256) void cvt_w(
    const float* __restrict__ W, ushort* __restrict__ WThi, ushort* __restrict__ WTlo)
{
  const int idx = blockIdx.x * 256 + threadIdx.x;   // 100*2048
  const int kc = idx >> 11, gcol = idx & 2047;
  u16x8 h = {0,0,0,0,0,0,0,0}, lo = {0,0,0,0,0,0,0,0};
#pragma unroll
  for (int e = 0; e < 8; ++e) {
    const int k = kc * 8 + e;
    if (k < Fn) {
      const float v = W[(size_t)k * G4n + gcol];
      const ushort hh = f2bf(v);
      h[e] = hh;
      lo[e] = f2bf(v - bf2f(hh));
    }
  }
  *(u16x8*)(WThi + (size_t)gcol * KP + kc * 8) = h;
  *(u16x8*)(WTlo + (size_t)gcol * KP + kc * 8) = lo;
}

// ---------------- K1: xzT[t][gcol][beta] = (x@W+b)^T via MFMA (R9, proven) ----------
__global__ __launch_bounds__(256, 2) void gemm_xz_mfma(
    const ushort* __restrict__ WThi, const ushort* __restrict__ WTlo,
    const ushort* __restrict__ xhi,  const ushort* __restrict__ xlo,
    const float* __restrict__ bias, float* __restrict__ xzT)
{
  const int tid = threadIdx.x;
  const int wv = tid >> 6, l = tid & 63;
  const int wr = wv >> 1, wc = wv & 1;
  const int gt  = blockIdx.x & 15;
  const int bgh = (blockIdx.x >> 4) & 1;
  const int t0  = blockIdx.x >> 5;
  const int g0 = gt * 128 + wr * 64;
  const int bg0 = bgh * 32 + wc * 16;
  const int t_base = t0 * 4;
  const int n = l & 15, kg = l >> 4;

  const ushort* pah = WThi + (size_t)(g0 + n) * KP + kg * 8;
  const ushort* pal = WTlo + (size_t)(g0 + n) * KP + kg * 8;
  const size_t mrow = ((size_t)(bg0 + n) * Tn + t_base) * KP + kg * 8;
  const ushort* pbh = xhi + mrow;
  const ushort* pbl = xlo + mrow;

  f32x4 acc[4][4] = {};
  for (int ks = 0; ks < 25; ++ks) {
    bf16x8 ah[4], al[4], bh[4], bl[4];
#pragma unroll
    for (int i = 0; i < 4; ++i) {
      const size_t ao = (size_t)i * 16 * KP + ks * 32;
      ah[i] = *(const bf16x8*)(pah + ao);
      al[i] = *(const bf16x8*)(pal + ao);
      const size_t bo = (size_t)i * KP + ks * 32;
      bh[i] = *(const bf16x8*)(pbh + bo);
      bl[i] = *(const bf16x8*)(pbl + bo);
    }
#pragma unroll
    for (int ai = 0; ai < 4; ++ai)
#pragma unroll
      for (int bj = 0; bj < 4; ++bj) {
        acc[ai][bj] = __builtin_amdgcn_mfma_f32_16x16x32_bf16(ah[ai], bh[bj], acc[ai][bj], 0, 0, 0);
        acc[ai][bj] = __builtin_amdgcn_mfma_f32_16x16x32_bf16(ah[ai], bl[bj], acc[ai][bj], 0, 0, 0);
        acc[ai][bj] = __builtin_amdgcn_mfma_f32_16x16x32_bf16(al[ai], bh[bj], acc[ai][bj], 0, 0, 0);
      }
  }
#pragma unroll
  for (int ai = 0; ai < 4; ++ai) {
#pragma unroll
    for (int r = 0; r < 4; ++r) {
      const int gc = g0 + ai * 16 + (kg << 2) + r;
      const float bb = bias[gc];
#pragma unroll
      for (int bj = 0; bj < 4; ++bj)
        xzT[((size_t)(t_base + bj) * G4n + gc) * Bn + bg0 + n] = acc[ai][bj][r] + bb;
    }
  }
}

// ---------------- K1-fallback: fp32 tiled ----------------
__global__ __launch_bounds__(256) void gemm_xz_f32(
    const float* __restrict__ A, const float* __restrict__ W,
    const float* __restrict__ bias, float* __restrict__ xzT)
{
  __shared__ float As[16][68];
  __shared__ float Bs[16][68];
  const int tid = threadIdx.x;
  const int tx = tid & 15, ty = tid >> 4;
  const int g0 = blockIdx.x * 64;
  const int tt = blockIdx.y;
  const int ar = tid >> 2, ac = (tid & 3) << 2;
  const int br = tid >> 4, bc = (tid & 15) << 2;
  float acc[4][4] = {};
  for (int kt = 0; kt < Fn; kt += 16) {
    const float4 a4 = *(const float4*)(A + ((size_t)ar * Tn + tt) * Fn + kt + ac);
    const float4 b4 = *(const float4*)(W + (size_t)(kt + br) * G4n + g0 + bc);
    __syncthreads();
    As[ac + 0][ar] = a4.x; As[ac + 1][ar] = a4.y;
    As[ac + 2][ar] = a4.z; As[ac + 3][ar] = a4.w;
    *(float4*)(&Bs[br][bc]) = b4;
    __syncthreads();
#pragma unroll
    for (int k = 0; k < 16; ++k) {
      const float4 av = *(const float4*)(&As[k][ty << 2]);
      const float4 bv = *(const float4*)(&Bs[k][tx << 2]);
      const float aarr[4] = {av.x, av.y, av.z, av.w};
      const float barr[4] = {bv.x, bv.y, bv.z, bv.w};
#pragma unroll
      for (int i = 0; i < 4; ++i)
#pragma unroll
        for (int j = 0; j < 4; ++j)
          acc[i][j] = fmaf(aarr[i], barr[j], acc[i][j]);
    }
  }
#pragma unroll
  for (int j = 0; j < 4; ++j) {
    const int gcol = g0 + (tx << 2) + j;
    const float bb = bias[gcol];
    float4 ov;
    ov.x = acc[0][j] + bb;
    ov.y = acc[1][j] + bb;
    ov.z = acc[2][j] + bb;
    ov.w = acc[3][j] + bb;
    *(float4*)(xzT + ((size_t)tt * G4n + gcol) * Bn + (ty << 2)) = ov;
  }
}

// ---------------- K2: MFMA LSTM, tag-flagged exchange, cluster-local ----------------
// 4 independent clusters (mt = blk>>4) of 16 blocks; cluster owns betas
// [16mt,+16). Block slice s = blk&15 owns h-cols [32s,+32); wave w owns h-cols
// [32s+4w,+4) (A-frag rows = 4 gates x 4 hcols). Exchange: hfrag slot =
// (tag = t+1)<<16 | bf16(h) -- one atomic uint: readers poll their own input
// slots until tag==t. No fences, no flags, no barrier. 2-buffer safe: a block
// reaches step t+1 only after seeing all read-slots tagged t+1, which implies
// every cluster block finished reading tags t (each lane writes only after its
// block's stage of tags t completed).
__global__ __launch_bounds__(512) void lstm_mfma(
    const float* __restrict__ xzT, const float* __restrict__ U,
    float* __restrict__ h_seq, uint* __restrict__ hfrag_u)
{
  __shared__ ushort hsm[8192];     // 16 KB: cluster h (bf16) in B-frag layout
  const int tid = threadIdx.x;
  const int blk = blockIdx.x;      // 0..63
  const int w = tid >> 6, l = tid & 63;
  const int n = l & 15, kg = l >> 4;
  const int mt = blk >> 4;         // cluster
  const int s  = blk & 15;         // hcol slice
  const int hc0 = (s << 5) + (w << 2);

  // ---- one-time: U^T A-fragments (bf16 hi+lo split) ----
  const int ugcol = ((n & 3) << 9) + hc0 + (n >> 2);
  bf16x8 ufhi[16], uflo[16];
#pragma unroll
  for (int ks = 0; ks < 16; ++ks) {
    bf16x8 hi, lo;
#pragma unroll
    for (int e = 0; e < 8; ++e) {
      const float u = U[(size_t)(32 * ks + 8 * kg + e) * G4n + ugcol];
      const ushort uh = f2bf(u);
      hi[e] = (short)uh;
      lo[e] = (short)f2bf(u - bf2f(uh));
    }
    ufhi[ks] = hi; uflo[ks] = lo;
  }

  const int beta = (mt << 4) + n;       // batch this lane owns
  const int hc   = hc0 + kg;            // h-col this lane owns
  float cst = 0.f;

  // B-frag-layout slot of (beta, hc) within cluster
  const uint slot = ((uint)(hc >> 5) * 64u + (uint)((hc & 31) >> 3) * 16u + (uint)n) * 8u
                    + (uint)(hc & 7);
  const uint cbase = (uint)mt * 8192u;

  float xzc[4];
#pragma unroll
  for (int r = 0; r < 4; ++r)
    xzc[r] = xzT[((size_t)(r << 9) + hc) * Bn + beta];   // t = 0

  for (int t = 0; t < Tn; ++t) {
    const uint rbuf = ((uint)t & 1u) * 32768u + cbase;
    const uint wbuf = ((uint)(t + 1) & 1u) * 32768u + cbase;
    const uint want = (uint)t;

    // prefetch next xz early (overlaps the poll)
    float xzn[4];
    if (t + 1 < Tn) {
#pragma unroll
      for (int r = 0; r < 4; ++r)
        xzn[r] = xzT[((size_t)(t + 1) * G4n + (r << 9) + hc) * Bn + beta];
    } else {
#pragma unroll
      for (int r = 0; r < 4; ++r) xzn[r] = 0.f;
    }

    // ---- poll+stage: 16 tagged uints per thread, parallel re-poll of stale ----
    uint vv[16];
    uint pend = 0xFFFFu;
    do {
#pragma unroll
      for (int j = 0; j < 16; ++j)
        if (pend & (1u << j))
          vv[j] = __hip_atomic_load(&hfrag_u[rbuf + (uint)tid + ((uint)j << 9)],
                                    __ATOMIC_RELAXED, __HIP_MEMORY_SCOPE_AGENT);
#pragma unroll
      for (int j = 0; j < 16; ++j)
        if ((pend & (1u << j)) && (vv[j] >> 16) == want) pend &= ~(1u << j);
    } while (pend);
#pragma unroll
    for (int j = 0; j < 16; ++j)
      hsm[tid + (j << 9)] = (ushort)(vv[j] & 0xFFFFu);
    __syncthreads();                    // stage complete

    // ---- MFMA: z^T = U^T (A, regs) x h^T (B, LDS) ----
    const bf16x8* bb = ((const bf16x8*)hsm) + l;
    f32x4 acch = {0.f, 0.f, 0.f, 0.f};
    f32x4 accl = {0.f, 0.f, 0.f, 0.f};
#pragma unroll
    for (int ks = 0; ks < 16; ++ks) {
      const bf16x8 bfr = bb[ks * 64];
      acch = __builtin_amdgcn_mfma_f32_16x16x32_bf16(ufhi[ks], bfr, acch, 0, 0, 0);
      accl = __builtin_amdgcn_mfma_f32_16x16x32_bf16(uflo[ks], bfr, accl, 0, 0, 0);
    }

    // reg r = gate r (Keras i,f,g,o) for (batch beta, hcol hc)
    const float zi = acch[0] + accl[0] + xzc[0];
    const float zf = acch[1] + accl[1] + xzc[1];
    const float zg = acch[2] + accl[2] + xzc[2];
    const float zo = acch[3] + accl[3] + xzc[3];
    const float iv = 1.f / (1.f + expf(-zi));
    const float fv = 1.f / (1.f + expf(-zf));
    const float gv = tanhf(zg);
    const float ov = 1.f / (1.f + expf(-zo));
    cst = fv * cst + iv * gv;
    const float hv = ov * tanhf(cst);

    h_seq[((size_t)beta * Tn + t) * Hn + hc] = hv;
    __hip_atomic_store(&hfrag_u[wbuf + slot],
                       (((uint)(t + 1)) << 16) | (uint)f2bf(hv),
                       __ATOMIC_RELAXED, __HIP_MEMORY_SCOPE_AGENT);

#pragma unroll
    for (int r = 0; r < 4; ++r) xzc[r] = xzn[r];
    __syncthreads();                    // all ds_reads done before next stage
  }
}

// ---------------- K3: out = h_seq @ Wd + bd ----------------
__global__ __launch_bounds__(256) void proj_out(
    const float* __restrict__ h_seq, const float* __restrict__ Wd,
    const float* __restrict__ bd, float* __restrict__ out)
{
  __shared__ float Wdt[10][516];
  for (int i = threadIdx.x; i < Hn * On; i += 256) {
    const int k = i / 10, o = i - k * 10;
    Wdt[o][k] = Wd[i];
  }
  __syncthreads();
  const int idx = blockIdx.x * 256 + threadIdx.x;
  const int row = idx / 10, o = idx - row * 10;
  const float* hp = h_seq + (size_t)row * Hn;
  const float* wp = &Wdt[o][0];
  float acc = bd[o];
#pragma unroll 4
  for (int k = 0; k < Hn; k += 4) {
    const float4 h4 = *(const float4*)(hp + k);
    const float4 w4 = *(const float4*)(wp + k);
    acc = fmaf(h4.x, w4.x, acc);
    acc = fmaf(h4.y, w4.y, acc);
    acc = fmaf(h4.z, w4.z, acc);
    acc = fmaf(h4.w, w4.w, acc);
  }
  out[idx] = acc;
}

extern "C" void kernel_launch(void* const* d_in, const int* in_sizes, int n_in,
                              void* d_out, int out_size, void* d_ws, size_t ws_size,
                              hipStream_t stream)
{
  const float* x  = (const float*)d_in[0];
  const float* W  = (const float*)d_in[1];
  const float* U  = (const float*)d_in[2];
  const float* b  = (const float*)d_in[3];
  const float* Wd = (const float*)d_in[4];
  const float* bd = (const float*)d_in[5];
  float* out = (float*)d_out;

  float* xzT    = (float*)d_ws;
  float* h_seq  = xzT + XZ_ELEMS;
  uint* hfrag_u = (uint*)(h_seq + HSEQ_ELEMS);      // 65536 tagged uints
  ushort* xhi  = (ushort*)h_seq;                    // overlap: dead until lstm
  ushort* xlo  = (ushort*)((char*)d_ws + BASE_END);
  ushort* WThi = xlo + (size_t)32768 * KP;
  ushort* WTlo = WThi + (size_t)G4n * KP;

  if (ws_size >= MFMA_END) {
    cvt_x<<<12800, 256, 0, stream>>>(x, xhi, xlo);
    cvt_w<<<800, 256, 0, stream>>>(W, WThi, WTlo);
    gemm_xz_mfma<<<4096, 256, 0, stream>>>(WThi, WTlo, xhi, xlo, b, xzT);
  } else {
    gemm_xz_f32<<<dim3(G4n / 64, Tn), 256, 0, stream>>>(x, W, b, xzT);
  }

  hipMemsetAsync(hfrag_u, 0, 65536 * sizeof(uint), stream);   // tags=0 -> h_{-1}=0
  lstm_mfma<<<dim3(NBLK), dim3(512), 0, stream>>>(xzT, U, h_seq, hfrag_u);

  proj_out<<<(Bn * Tn * On) / 256, 256, 0, stream>>>(h_seq, Wd, bd, out);
}